// Round 1
// baseline (28.042 us; speedup 1.0000x reference)
//
#include <hip/hip_runtime.h>
#include <math.h>

// FraudDetectionNet: per-2x2-patch 4-qubit circuit -> Z expectations -> linear -> sigmoid.
// One block of 256 threads per image (196 active patch threads), block-reduce, sigmoid.

__global__ __launch_bounds__(256) void fraud_kernel(
    const float* __restrict__ x,     // (B,1,28,28) fp32
    const float* __restrict__ W,     // (784,1) fp32
    const float* __restrict__ bias,  // (1,)  fp32
    float* __restrict__ out)         // (B,)  fp32
{
    const int img_idx = blockIdx.x;
    const int tid = threadIdx.x;

    float partial = 0.0f;

    if (tid < 196) {
        const int i = tid / 14;        // patch row
        const int j = tid - i * 14;    // patch col
        const float* img = x + (size_t)img_idx * 784 + (2 * i) * 28 + 2 * j;

        const float2 r0 = *reinterpret_cast<const float2*>(img);        // img[2i, 2j..2j+1]
        const float2 r1 = *reinterpret_cast<const float2*>(img + 28);   // img[2i+1, 2j..2j+1]
        const float pv[4] = { r0.x, r0.y, r1.x, r1.y };

        // half-angle = clip(p,-1,1) * pi/2 ; cos/sin via native hw trig (|x| <= pi/2, no range reduction needed)
        float c[4], s[4];
        #pragma unroll
        for (int q = 0; q < 4; ++q) {
            const float h = fminf(fmaxf(pv[q], -1.0f), 1.0f) * 1.5707963267948966f;
            s[q] = __sinf(h);
            c[q] = __cosf(h);
        }

        // State after first RY layer on |0000>: product state.
        // wire q <-> bit (3-q): st[b] = f0(bit3)*f1(bit2)*f2(bit1)*f3(bit0), f=(bit? s : c)
        float st[16];
        {
            const float hi[4] = { c[0]*c[1], c[0]*s[1], s[0]*c[1], s[0]*s[1] }; // (bit3,bit2)
            const float lo[4] = { c[2]*c[3], c[2]*s[3], s[2]*c[3], s[2]*s[3] }; // (bit1,bit0)
            #pragma unroll
            for (int h = 0; h < 4; ++h)
                #pragma unroll
                for (int l = 0; l < 4; ++l)
                    st[h * 4 + l] = hi[h] * lo[l];
        }

        // 3 x [RY layer on all wires, CNOT(0,1), CNOT(2,3)]
        #pragma unroll
        for (int layer = 0; layer < 3; ++layer) {
            #pragma unroll
            for (int q = 0; q < 4; ++q) {
                const int m = 8 >> q;   // wire q acts on bit (3-q)
                #pragma unroll
                for (int b = 0; b < 16; ++b) {
                    if (b & m) continue;
                    const float a0 = st[b];
                    const float a1 = st[b | m];
                    st[b]     = c[q] * a0 - s[q] * a1;
                    st[b | m] = s[q] * a0 + c[q] * a1;
                }
            }
            // CNOT(c=0,t=1): for bit3 set, b <-> b^4
            #pragma unroll
            for (int k = 0; k < 4; ++k) {
                const float t = st[8 + k]; st[8 + k] = st[12 + k]; st[12 + k] = t;
            }
            // CNOT(c=2,t=3): for bit1 set, b <-> b^1
            {
                float t;
                t = st[2];  st[2]  = st[3];  st[3]  = t;
                t = st[6];  st[6]  = st[7];  st[7]  = t;
                t = st[10]; st[10] = st[11]; st[11] = t;
                t = st[14]; st[14] = st[15]; st[15] = t;
            }
        }

        // partial = sum_q z_q * W[4p+q] = sum_b st[b]^2 * coef[b],
        // coef[b] = (bit3?-w0:+w0)+(bit2?-w1:+w1)+(bit1?-w2:+w2)+(bit0?-w3:+w3)
        const float4 w4 = *reinterpret_cast<const float4*>(W + 4 * tid);
        float e01[4], e23[4];
        e01[0] =  w4.x + w4.y;  e01[1] =  w4.x - w4.y;
        e01[2] = -w4.x + w4.y;  e01[3] = -w4.x - w4.y;
        e23[0] =  w4.z + w4.w;  e23[1] =  w4.z - w4.w;
        e23[2] = -w4.z + w4.w;  e23[3] = -w4.z - w4.w;
        #pragma unroll
        for (int b = 0; b < 16; ++b) {
            const float coef = e01[b >> 2] + e23[b & 3];
            partial = fmaf(st[b] * st[b], coef, partial);
        }
    }

    // Block reduction: 4 waves of 64
    #pragma unroll
    for (int off = 32; off > 0; off >>= 1)
        partial += __shfl_xor(partial, off, 64);

    __shared__ float red[4];
    const int wave = tid >> 6;
    if ((tid & 63) == 0) red[wave] = partial;
    __syncthreads();

    if (tid == 0) {
        const float v = red[0] + red[1] + red[2] + red[3] + bias[0];
        out[img_idx] = 1.0f / (1.0f + __expf(-v));
    }
}

extern "C" void kernel_launch(void* const* d_in, const int* in_sizes, int n_in,
                              void* d_out, int out_size, void* d_ws, size_t ws_size,
                              hipStream_t stream) {
    const float* x    = (const float*)d_in[0];
    const float* W    = (const float*)d_in[1];
    const float* bias = (const float*)d_in[2];
    float* out = (float*)d_out;

    const int B = out_size;  // 8192
    fraud_kernel<<<dim3(B), dim3(256), 0, stream>>>(x, W, bias, out);
}

// Round 2
// 23.142 us; speedup vs baseline: 1.2117x; 1.2117x over previous
//
#include <hip/hip_runtime.h>
#include <math.h>

// FraudDetectionNet: per-2x2-patch 4-qubit circuit -> Z expectations -> linear -> sigmoid.
// Patch-parallel: 1 thread per (image,patch), full 64-lane utilization.
// Circuit folding: reference applies 4 identical RY layers (init + 3 in loop);
// the first two are adjacent => collapse to product state with double angles
// (c2 = 1-2s^2, s2 = 2cs), then 2 x [RY layer + CNOTs].
//
// Reduction (deterministic, no atomics): a wave covers 64 consecutive patches,
// spanning at most 2 images (196 patches/img > 64). Butterfly-reduce two masked
// accumulators, write float2 per wave into d_ws; finish kernel gathers <=5
// wave-partials per image, adds bias, sigmoid.

#define B_IMG   8192
#define NPATCH  196
#define NP_TOT  (B_IMG * NPATCH)     // 1,605,632 = 64 * 25,088
#define NWAVE   (NP_TOT / 64)        // 25,088

__global__ __launch_bounds__(256) void patch_kernel(
    const float* __restrict__ x,     // (B,1,28,28)
    const float* __restrict__ W,     // (784,1)
    float2* __restrict__ wsum)       // (NWAVE) per-wave {sum_imgFirst, sum_imgLast}
{
    const int gtid = blockIdx.x * 256 + threadIdx.x;
    const int lane = threadIdx.x & 63;
    const int gw   = gtid >> 6;

    const unsigned p   = (unsigned)gtid;
    const unsigned img = p / 196u;
    const unsigned pi  = p - img * 196u;
    const unsigned i   = pi / 14u;
    const unsigned j   = pi - i * 14u;

    const float* imgp = x + (size_t)img * 784 + (2u * i) * 28 + 2u * j;
    const float2 r0 = *reinterpret_cast<const float2*>(imgp);
    const float2 r1 = *reinterpret_cast<const float2*>(imgp + 28);
    const float pv[4] = { r0.x, r0.y, r1.x, r1.y };

    // half-angle = clip(p,-1,1)*pi/2 ; in revolutions: t*0.25
    float ch[4], sh[4], c2[4], s2[4];
    #pragma unroll
    for (int q = 0; q < 4; ++q) {
        const float t = fminf(fmaxf(pv[q], -1.0f), 1.0f);
        const float r = t * 0.25f;                     // revolutions
        sh[q] = __builtin_amdgcn_sinf(r);              // sin(t*pi/2)
        ch[q] = __builtin_amdgcn_cosf(r);              // cos(t*pi/2)
        const float tm = sh[q] + sh[q];
        c2[q] = fmaf(-tm, sh[q], 1.0f);                // cos(t*pi) = 1-2s^2
        s2[q] = tm * ch[q];                            // sin(t*pi) = 2cs
    }

    // Product state after two fused RY layers: st[b] = f0(b3)f1(b2)f2(b1)f3(b0)
    float st[16];
    {
        const float hi[4] = { c2[0]*c2[1], c2[0]*s2[1], s2[0]*c2[1], s2[0]*s2[1] };
        const float lo[4] = { c2[2]*c2[3], c2[2]*s2[3], s2[2]*c2[3], s2[2]*s2[3] };
        #pragma unroll
        for (int h = 0; h < 4; ++h)
            #pragma unroll
            for (int l = 0; l < 4; ++l)
                st[h * 4 + l] = hi[h] * lo[l];
    }

    // CNOT(0,1): bit3 set -> b ^= 4 ; CNOT(2,3): bit1 set -> b ^= 1
    #pragma unroll
    for (int k = 0; k < 4; ++k) { const float t = st[8+k]; st[8+k] = st[12+k]; st[12+k] = t; }
    { float t;
      t = st[2];  st[2]  = st[3];  st[3]  = t;
      t = st[6];  st[6]  = st[7];  st[7]  = t;
      t = st[10]; st[10] = st[11]; st[11] = t; 
      t = st[14]; st[14] = st[15]; st[15] = t; }

    // 2 remaining [RY layer + CNOTs] with half-angle (ch, sh)
    #pragma unroll
    for (int layer = 0; layer < 2; ++layer) {
        #pragma unroll
        for (int q = 0; q < 4; ++q) {
            const int m = 8 >> q;
            #pragma unroll
            for (int b = 0; b < 16; ++b) {
                if (b & m) continue;
                const float a0 = st[b];
                const float a1 = st[b | m];
                st[b]     = ch[q] * a0 - sh[q] * a1;
                st[b | m] = sh[q] * a0 + ch[q] * a1;
            }
        }
        #pragma unroll
        for (int k = 0; k < 4; ++k) { const float t = st[8+k]; st[8+k] = st[12+k]; st[12+k] = t; }
        { float t;
          t = st[2];  st[2]  = st[3];  st[3]  = t;
          t = st[6];  st[6]  = st[7];  st[7]  = t;
          t = st[10]; st[10] = st[11]; st[11] = t;
          t = st[14]; st[14] = st[15]; st[15] = t; }
    }

    // partial = sum_b st[b]^2 * coef[b],
    // coef[b] = (b3?-w0:+w0)+(b2?-w1:+w1)+(b1?-w2:+w2)+(b0?-w3:+w3)
    const float4 w4 = *reinterpret_cast<const float4*>(W + 4u * pi);
    float e01[4], e23[4];
    e01[0] =  w4.x + w4.y;  e01[1] =  w4.x - w4.y;
    e01[2] = -w4.x + w4.y;  e01[3] = -w4.x - w4.y;
    e23[0] =  w4.z + w4.w;  e23[1] =  w4.z - w4.w;
    e23[2] = -w4.z + w4.w;  e23[3] = -w4.z - w4.w;
    float partial = 0.0f;
    #pragma unroll
    for (int b = 0; b < 16; ++b)
        partial = fmaf(st[b] * st[b], e01[b >> 2] + e23[b & 3], partial);

    // Segmented wave reduce: wave spans at most 2 images.
    const unsigned imgF = __shfl(img, 0, 64);
    float va = (img == imgF) ? partial : 0.0f;
    float vb = partial - va;
    #pragma unroll
    for (int off = 32; off > 0; off >>= 1) {
        va += __shfl_xor(va, off, 64);
        vb += __shfl_xor(vb, off, 64);
    }
    if (lane == 0) wsum[gw] = make_float2(va, vb);
}

__global__ __launch_bounds__(256) void finish_kernel(
    const float2* __restrict__ wsum,
    const float* __restrict__ bias,
    float* __restrict__ out)
{
    const unsigned i = blockIdx.x * 256 + threadIdx.x;   // 8192 images
    if (i >= B_IMG) return;
    const unsigned lo = (i * 196u) >> 6;
    const unsigned hi = (i * 196u + 195u) >> 6;
    float acc = bias[0];
    for (unsigned w = lo; w <= hi; ++w) {     // <= 5 iterations
        const float2 s = wsum[w];
        const unsigned f = (w * 64u) / 196u;
        const unsigned l = (w * 64u + 63u) / 196u;
        if (f == i) acc += s.x;
        if (l == i && l != f) acc += s.y;
    }
    out[i] = 1.0f / (1.0f + __expf(-acc));
}

extern "C" void kernel_launch(void* const* d_in, const int* in_sizes, int n_in,
                              void* d_out, int out_size, void* d_ws, size_t ws_size,
                              hipStream_t stream) {
    const float* x    = (const float*)d_in[0];
    const float* W    = (const float*)d_in[1];
    const float* bias = (const float*)d_in[2];
    float* out = (float*)d_out;
    float2* wsum = (float2*)d_ws;            // NWAVE * 8 B = 200 KB scratch

    patch_kernel<<<dim3(NP_TOT / 256), dim3(256), 0, stream>>>(x, W, wsum);
    finish_kernel<<<dim3((B_IMG + 255) / 256), dim3(256), 0, stream>>>(wsum, bias, out);
}